// Round 11
// baseline (763.315 us; speedup 1.0000x reference)
//
#include <hip/hip_runtime.h>

typedef __bf16 bf16;
typedef __attribute__((ext_vector_type(8))) __bf16 bf16x8;
typedef __attribute__((ext_vector_type(4))) __bf16 bf16x4;
typedef __attribute__((ext_vector_type(4))) float  f32x4;

// ---------- helpers ----------
__device__ __forceinline__ f32x4 mfma16(bf16x8 a, bf16x8 b, f32x4 c) {
    return __builtin_amdgcn_mfma_f32_16x16x32_bf16(a, b, c, 0, 0, 0);
}

__device__ __forceinline__ void stash8(bf16* dst, float4 a, float4 b) {
    bf16x8 v;
    v[0] = (bf16)a.x; v[1] = (bf16)a.y; v[2] = (bf16)a.z; v[3] = (bf16)a.w;
    v[4] = (bf16)b.x; v[5] = (bf16)b.y; v[6] = (bf16)b.z; v[7] = (bf16)b.w;
    *reinterpret_cast<bf16x8*>(dst) = v;
}

// async global->LDS, 16B per lane, zero VGPR cost for the data
__device__ __forceinline__ void glds16(const float* g, float* l) {
    __builtin_amdgcn_global_load_lds((__attribute__((address_space(1))) const void*)g,
                                     (__attribute__((address_space(3))) void*)l, 16, 0, 0);
}

// B-fragment from PRE-SWIZZLED weights: 64 lanes read one contiguous 1KB block.
__device__ __forceinline__ bf16x8 wfrag(const bf16* __restrict__ W, int s, int n, int lane) {
    return *reinterpret_cast<const bf16x8*>(W + (((s * 4 + n) * 64 + lane) * 8));
}

// 2-M-tile x 4-N-tile MFMA matmul; A from LDS (pitch P), B swizzled, KS k-steps.
template<int P, int KS>
__device__ __forceinline__ void mm2s(const bf16* __restrict__ src, int kofs,
                                     const bf16* __restrict__ W,
                                     int lane, f32x4 (&acc)[2][4]) {
    const int c16 = lane & 15, g = lane >> 4;
#pragma unroll
    for (int m = 0; m < 2; ++m)
#pragma unroll
        for (int n = 0; n < 4; ++n) acc[m][n] = 0.0f;
#pragma unroll
    for (int s = 0; s < KS; ++s) {
        bf16x8 aA = *reinterpret_cast<const bf16x8*>(src + c16 * P + kofs + s * 32 + g * 8);
        bf16x8 aB = *reinterpret_cast<const bf16x8*>(src + (16 + c16) * P + kofs + s * 32 + g * 8);
#pragma unroll
        for (int n = 0; n < 4; ++n) {
            bf16x8 bb = wfrag(W, s, n, lane);
            acc[0][n] = mfma16(aA, bb, acc[0][n]);
            acc[1][n] = mfma16(aB, bb, acc[1][n]);
        }
    }
}

template<int P, int KS>
__device__ __forceinline__ void mm1s(const bf16* __restrict__ src, int kofs,
                                     const bf16* __restrict__ W,
                                     int lane, f32x4 (&acc)[4]) {
    const int c16 = lane & 15, g = lane >> 4;
#pragma unroll
    for (int n = 0; n < 4; ++n) acc[n] = 0.0f;
#pragma unroll
    for (int s = 0; s < KS; ++s) {
        bf16x8 a = *reinterpret_cast<const bf16x8*>(src + c16 * P + kofs + s * 32 + g * 8);
#pragma unroll
        for (int n = 0; n < 4; ++n) {
            bf16x8 bb = wfrag(W, s, n, lane);
            acc[n] = mfma16(a, bb, acc[n]);
        }
    }
}

__device__ __forceinline__ void storeh2(bf16* hbw, const f32x4 (&acc)[2][4],
                                        const float* __restrict__ bias, int c16, int g) {
#pragma unroll
    for (int n = 0; n < 4; ++n) {
        float bb = bias[n * 16 + c16];
#pragma unroll
        for (int m = 0; m < 2; ++m)
#pragma unroll
            for (int r = 0; r < 4; ++r)
                hbw[(m * 16 + g * 4 + r) * 72 + n * 16 + c16] = (bf16)fmaxf(acc[m][n][r] + bb, 0.0f);
    }
}

__device__ __forceinline__ void storeh1(bf16* hbw, const f32x4 (&acc)[4],
                                        const float* __restrict__ bias, int c16, int g) {
#pragma unroll
    for (int n = 0; n < 4; ++n) {
        float bb = bias[n * 16 + c16];
#pragma unroll
        for (int r = 0; r < 4; ++r)
            hbw[(g * 4 + r) * 72 + n * 16 + c16] = (bf16)fmaxf(acc[n][r] + bb, 0.0f);
    }
}

// ---------- setup: weight swizzle + x->bf16 copy + degree count (fused) ----------
struct PrepArgs {
    const float* src[10];
    bf16* dst[10];
    int ofs[11];
    int ldk[10];
};

__global__ __launch_bounds__(256) void setup_kernel(PrepArgs a, int totalFrag,
                                                    const float* __restrict__ x,
                                                    bf16* __restrict__ xbuf, int total8,
                                                    const int* __restrict__ ei,
                                                    int* __restrict__ deg, int E) {
    int t = blockIdx.x * 256 + threadIdx.x;
    if (t < totalFrag) {
        int eb = t * 8;
        int k = 0;
        while (k < 9 && eb >= a.ofs[k + 1]) ++k;
        int f = (eb - a.ofs[k]) >> 3;
        int lane = f & 63, n = (f >> 6) & 3, s = f >> 8;
        int c16 = lane & 15, g = lane >> 4;
        const float* sp = a.src[k] + (n * 16 + c16) * a.ldk[k] + s * 32 + g * 8;
        float4 v0 = *reinterpret_cast<const float4*>(sp);
        float4 v1 = *reinterpret_cast<const float4*>(sp + 4);
        stash8(a.dst[k] + (size_t)f * 8, v0, v1);
        return;
    }
    t -= totalFrag;
    if (t < total8) {
        const float4* p = reinterpret_cast<const float4*>(x) + t * 2;
        stash8(xbuf + (size_t)t * 8, p[0], p[1]);
        return;
    }
    t -= total8;
    if (t < E) atomicAdd(&deg[ei[E + t]], 1);
}

// ---------- CSR scan ----------
__global__ __launch_bounds__(256) void scan1_kernel(const int* __restrict__ deg, int* __restrict__ ofs,
                                                    int* __restrict__ bsum, int N) {
    __shared__ int ws4[4];
    const int t = threadIdx.x, lane = t & 63, w = t >> 6;
    const int i = blockIdx.x * 256 + t;
    const int v = (i < N) ? deg[i] : 0;
    int inc = v;
#pragma unroll
    for (int o = 1; o < 64; o <<= 1) { int u = __shfl_up(inc, o); if (lane >= o) inc += u; }
    if (lane == 63) ws4[w] = inc;
    __syncthreads();
    int add = 0;
    for (int k = 0; k < w; ++k) add += ws4[k];
    if (i < N) ofs[i] = inc - v + add;
    if (t == 255) bsum[blockIdx.x] = inc + add;
}

__global__ __launch_bounds__(256) void scan2_kernel(int* __restrict__ bsum, int nb) {
    __shared__ int ws4[4];
    const int t = threadIdx.x, lane = t & 63, w = t >> 6;
    const int v = (t < nb) ? bsum[t] : 0;
    int inc = v;
#pragma unroll
    for (int o = 1; o < 64; o <<= 1) { int u = __shfl_up(inc, o); if (lane >= o) inc += u; }
    if (lane == 63) ws4[w] = inc;
    __syncthreads();
    int add = 0;
    for (int k = 0; k < w; ++k) add += ws4[k];
    if (t < nb) bsum[t] = inc - v + add;
}

__global__ __launch_bounds__(256) void scan3_kernel(int* __restrict__ ofs, const int* __restrict__ bsum, int N) {
    const int i = blockIdx.x * 256 + threadIdx.x;
    if (i < N) ofs[i] += bsum[blockIdx.x];
}

// ---------- CSR fill ----------
__global__ __launch_bounds__(256) void fill_kernel(const int* __restrict__ ei, const int* __restrict__ ofs,
                                                   int* __restrict__ cur, int* __restrict__ eidT, int E) {
    const int e = blockIdx.x * 256 + threadIdx.x;
    if (e >= E) return;
    const int d = ei[E + e];
    const int slot = atomicAdd(&cur[d], 1);
    eidT[ofs[d] + slot] = e;
}

// ---------- E1: r8 body + async global_load_lds ea pipeline (zero-VGPR prefetch) ----------
template<int T>
__global__ __launch_bounds__(256, 3) void e1_kernel(
    const bf16* __restrict__ xb, const int* __restrict__ ei, const float* __restrict__ ea,
    const bf16* __restrict__ W0, const bf16* __restrict__ W1, const bf16* __restrict__ W2,
    const bf16* __restrict__ Wq, const bf16* __restrict__ Wk, const bf16* __restrict__ Wv,
    const float* __restrict__ b0, const float* __restrict__ b1, const float* __restrict__ b2,
    const float* __restrict__ egm, const float* __restrict__ ebe,
    float* __restrict__ scoresOut, bf16* __restrict__ Vout, float* __restrict__ eout,
    int tileOfs, int E)
{
    __shared__ float stg[4][2048];    // per-wave async ea staging (8KB, f32, linear)
    __shared__ bf16 eas[4][32][72];   // edge_attr rows (bf16), pitch 72
    __shared__ bf16 hbl[4][32][72];   // inter-layer transpose buffer, pitch 72
    const int w = threadIdx.x >> 6;
    const int lane = threadIdx.x & 63;
    const int g = lane >> 4, c16 = lane & 15;
    const int rr = lane >> 4, cc = (lane & 15) * 4;
    float* stgw = &stg[w][0];
    bf16* eaw = &eas[w][0][0];
    bf16* hbw = &hbl[w][0][0];
    const int tile0 = tileOfs + blockIdx.x * T;

    // ---- prologue: async-stage tile0's ea; load tile0's edge indices
    {
        const size_t gb = (size_t)(tile0 * 128 + w * 32) * 64;
#pragma unroll
        for (int j = 0; j < 8; ++j)
            glds16(ea + gb + j * 256 + lane * 4, stgw + j * 256);
    }
    int dn0, dn1, sn0, sn1;
    {
        const int tb = tile0 * 128 + w * 32;
        dn0 = ei[E + tb + c16]; dn1 = ei[E + tb + 16 + c16];
        sn0 = ei[tb + c16];     sn1 = ei[tb + 16 + c16];
    }

    for (int k = 0; k < T; ++k) {
        const int ebase = (tile0 + k) * 128 + w * 32;

        // ---- issue current tile's x-fragment loads (indices already resident)
        bf16x8 fxd[2][2], fxs[2][2];
#pragma unroll
        for (int s = 0; s < 2; ++s) {
            fxd[0][s] = *reinterpret_cast<const bf16x8*>(xb + (size_t)dn0 * 64 + s * 32 + g * 8);
            fxd[1][s] = *reinterpret_cast<const bf16x8*>(xb + (size_t)dn1 * 64 + s * 32 + g * 8);
            fxs[0][s] = *reinterpret_cast<const bf16x8*>(xb + (size_t)sn0 * 64 + s * 32 + g * 8);
            fxs[1][s] = *reinterpret_cast<const bf16x8*>(xb + (size_t)sn1 * 64 + s * 32 + g * 8);
        }

        // ---- staged ea (arrived long ago) -> bf16 eas
        asm volatile("s_waitcnt vmcnt(0)" ::: "memory");
        __builtin_amdgcn_sched_barrier(0);
#pragma unroll
        for (int j = 0; j < 8; ++j) {
            int row = j * 4 + rr;
            float4 v = *reinterpret_cast<const float4*>(stgw + row * 64 + cc);
            bf16x4 o;
            o[0] = (bf16)v.x; o[1] = (bf16)v.y; o[2] = (bf16)v.z; o[3] = (bf16)v.w;
            *reinterpret_cast<bf16x4*>(eaw + row * 72 + cc) = o;
        }
        asm volatile("s_waitcnt lgkmcnt(0)" ::: "memory");
        __builtin_amdgcn_sched_barrier(0);

        // ---- issue NEXT tile's async ea staging + ei prefetch (in flight all tile)
        int ndn0, ndn1, nsn0, nsn1;
        if (k + 1 < T) {
            const int nb2 = ebase + 128;
            const size_t gb = (size_t)nb2 * 64;
#pragma unroll
            for (int j = 0; j < 8; ++j)
                glds16(ea + gb + j * 256 + lane * 4, stgw + j * 256);
            ndn0 = ei[E + nb2 + c16]; ndn1 = ei[E + nb2 + 16 + c16];
            nsn0 = ei[nb2 + c16];     nsn1 = ei[nb2 + 16 + c16];
        }

        // ---- Q/K + per-head scores; LDS-staged 512B contiguous store
        {
            f32x4 aq[2][4], ak[2][4];
#pragma unroll
            for (int m = 0; m < 2; ++m)
#pragma unroll
                for (int n = 0; n < 4; ++n) { aq[m][n] = 0.0f; ak[m][n] = 0.0f; }
#pragma unroll
            for (int s = 0; s < 2; ++s)
#pragma unroll
                for (int n = 0; n < 4; ++n) {
                    bf16x8 bq = wfrag(Wq, s, n, lane);
                    bf16x8 bk = wfrag(Wk, s, n, lane);
                    aq[0][n] = mfma16(fxd[0][s], bq, aq[0][n]);
                    aq[1][n] = mfma16(fxd[1][s], bq, aq[1][n]);
                    ak[0][n] = mfma16(fxs[0][s], bk, ak[0][n]);
                    ak[1][n] = mfma16(fxs[1][s], bk, ak[1][n]);
                }
            float* sst = reinterpret_cast<float*>(hbw);
#pragma unroll
            for (int n = 0; n < 4; ++n) {
#pragma unroll
                for (int m = 0; m < 2; ++m) {
                    float pr[4];
#pragma unroll
                    for (int r = 0; r < 4; ++r) pr[r] = aq[m][n][r] * ak[m][n][r];
#pragma unroll
                    for (int ms = 1; ms < 16; ms <<= 1)
#pragma unroll
                        for (int r = 0; r < 4; ++r) pr[r] += __shfl_xor(pr[r], ms);
                    if (c16 == n) {
#pragma unroll
                        for (int r = 0; r < 4; ++r)
                            sst[(m * 16 + g * 4 + r) * 4 + n] = pr[r] * 0.25f;  // / sqrt(16)
                    }
                }
            }
            float2 sv = *reinterpret_cast<const float2*>(sst + lane * 2);
            *reinterpret_cast<float2*>(scoresOut + (size_t)ebase * 4 + lane * 2) = sv;
        }

        // ---- L0: W0 * [xd | xs | ea]  (K = 192)
        f32x4 acc[2][4], acc2[2][4];
#pragma unroll
        for (int m = 0; m < 2; ++m)
#pragma unroll
            for (int n = 0; n < 4; ++n) acc[m][n] = 0.0f;
#pragma unroll
        for (int s = 0; s < 2; ++s)
#pragma unroll
            for (int n = 0; n < 4; ++n) {
                bf16x8 bd = wfrag(W0, s, n, lane);
                acc[0][n] = mfma16(fxd[0][s], bd, acc[0][n]);
                acc[1][n] = mfma16(fxd[1][s], bd, acc[1][n]);
                bf16x8 bs = wfrag(W0, s + 2, n, lane);
                acc[0][n] = mfma16(fxs[0][s], bs, acc[0][n]);
                acc[1][n] = mfma16(fxs[1][s], bs, acc[1][n]);
            }
#pragma unroll
        for (int s = 0; s < 2; ++s) {
            bf16x8 ae0 = *reinterpret_cast<const bf16x8*>(eaw + c16 * 72 + s * 32 + g * 8);
            bf16x8 ae1 = *reinterpret_cast<const bf16x8*>(eaw + (16 + c16) * 72 + s * 32 + g * 8);
#pragma unroll
            for (int n = 0; n < 4; ++n) {
                bf16x8 be = wfrag(W0, s + 4, n, lane);
                acc[0][n] = mfma16(ae0, be, acc[0][n]);
                acc[1][n] = mfma16(ae1, be, acc[1][n]);
            }
        }

        // ---- relu -> L1 -> relu -> L2 + b2
        storeh2(hbw, acc, b0, c16, g);
        mm2s<72, 2>(hbw, 0, W1, lane, acc);
        storeh2(hbw, acc, b1, c16, g);
        mm2s<72, 2>(hbw, 0, W2, lane, acc2);
#pragma unroll
        for (int n = 0; n < 4; ++n) {
            float bb = b2[n * 16 + c16];
#pragma unroll
            for (int m = 0; m < 2; ++m)
#pragma unroll
                for (int r = 0; r < 4; ++r) acc2[m][n][r] += bb;
        }

        // ---- LayerNorm per edge row
        float mu[2][4], rs[2][4];
#pragma unroll
        for (int m = 0; m < 2; ++m)
#pragma unroll
            for (int r = 0; r < 4; ++r) {
                float s1 = acc2[m][0][r] + acc2[m][1][r] + acc2[m][2][r] + acc2[m][3][r];
                for (int ms = 1; ms < 16; ms <<= 1) s1 += __shfl_xor(s1, ms);
                float mm = s1 * (1.0f / 64.0f);
                float d0 = acc2[m][0][r] - mm, d1 = acc2[m][1][r] - mm;
                float d2 = acc2[m][2][r] - mm, d3 = acc2[m][3][r] - mm;
                float sq = d0 * d0 + d1 * d1 + d2 * d2 + d3 * d3;
                for (int ms = 1; ms < 16; ms <<= 1) sq += __shfl_xor(sq, ms);
                mu[m][r] = mm;
                rs[m][r] = rsqrtf(sq * (1.0f / 64.0f) + 1e-5f);
            }

        // ---- e_new -> hbl (A-layout, bf16)
#pragma unroll
        for (int n = 0; n < 4; ++n) {
            float gg = egm[n * 16 + c16], bb = ebe[n * 16 + c16];
#pragma unroll
            for (int m = 0; m < 2; ++m)
#pragma unroll
                for (int r = 0; r < 4; ++r) {
                    int rowi = m * 16 + g * 4 + r;
                    float v = (acc2[m][n][r] - mu[m][r]) * rs[m][r] * gg + bb;
                    hbw[rowi * 72 + n * 16 + c16] = (bf16)v;
                }
        }

        // ---- eout = edge_attr + e_new; 1KB-contiguous stores
#pragma unroll
        for (int i = 0; i < 8; ++i) {
            int row = i * 4 + rr;
            bf16x4 hv = *reinterpret_cast<const bf16x4*>(hbw + row * 72 + cc);
            bf16x4 av = *reinterpret_cast<const bf16x4*>(eaw + row * 72 + cc);
            float4 o;
            o.x = (float)av[0] + (float)hv[0];
            o.y = (float)av[1] + (float)hv[1];
            o.z = (float)av[2] + (float)hv[2];
            o.w = (float)av[3] + (float)hv[3];
            *reinterpret_cast<float4*>(eout + (size_t)(ebase + row) * 64 + cc) = o;
        }

        // ---- V = e_new @ wv.T ; 1KB-contiguous stores (stages into eaw, now dead)
        mm2s<72, 2>(hbw, 0, Wv, lane, acc);
#pragma unroll
        for (int n = 0; n < 4; ++n)
#pragma unroll
            for (int m = 0; m < 2; ++m)
#pragma unroll
                for (int r = 0; r < 4; ++r)
                    eaw[(m * 16 + g * 4 + r) * 72 + n * 16 + c16] = (bf16)acc[m][n][r];
#pragma unroll
        for (int kk = 0; kk < 4; ++kk) {
            int row = kk * 8 + (lane >> 3);
            int col = (lane & 7) * 8;
            bf16x8 v = *reinterpret_cast<const bf16x8*>(eaw + row * 72 + col);
            *reinterpret_cast<bf16x8*>(Vout + (size_t)(ebase + row) * 64 + col) = v;
        }

        if (k + 1 < T) { dn0 = ndn0; dn1 = ndn1; sn0 = nsn0; sn1 = nsn1; }
    }
}

// ---------- gather: per-node online softmax; V/scores via eidT (random reads, L3) ----------
__global__ __launch_bounds__(256) void gather_kernel(
    const int* __restrict__ deg, const int* __restrict__ ofs, const int* __restrict__ eidT,
    const float* __restrict__ scores, const bf16* __restrict__ V,
    bf16* __restrict__ msg, int N)
{
    const int w = threadIdx.x >> 6, lane = threadIdx.x & 63;
    const int n = blockIdx.x * 4 + w;
    if (n >= N) return;
    const int cnt = deg[n];
    const int* lst = eidT + ofs[n];
    const int h = lane >> 4;
    float m = -3.4e38f, s = 0.f, acc = 0.f;

    int eA = (lane < cnt) ? lst[lane] : 0;
    int eB = (64 + lane < cnt) ? lst[64 + lane] : 0;
    const int nr = min(cnt, 128);
    if (nr > 0) {
        int e = __shfl(eA, 0);
        float sc = scores[(size_t)e * 4 + h];
        float v  = (float)V[(size_t)e * 64 + lane];
        for (int i = 1; i <= nr; ++i) {
            float sc2 = 0.f, v2 = 0.f;
            if (i < nr) {
                int e2 = __shfl((i < 64) ? eA : eB, i & 63);
                sc2 = scores[(size_t)e2 * 4 + h];
                v2  = (float)V[(size_t)e2 * 64 + lane];
            }
            float mn = fmaxf(m, sc);
            float c  = __expf(m - mn);
            float ex = __expf(sc - mn);
            s = s * c + ex;
            acc = acc * c + ex * v;
            m = mn;
            sc = sc2; v = v2;
        }
    }
    for (int i = 128; i < cnt; ++i) {
        int e = lst[i];
        float sc = scores[(size_t)e * 4 + h];
        float v  = (float)V[(size_t)e * 64 + lane];
        float mn = fmaxf(m, sc);
        float c  = __expf(m - mn);
        float ex = __expf(sc - mn);
        s = s * c + ex;
        acc = acc * c + ex * v;
        m = mn;
    }
    msg[(size_t)n * 64 + lane] = (bf16)(acc / (s + 1e-12f));
}

// ---------- N: node MLP ----------
__global__ __launch_bounds__(256, 4) void n_kernel(
    const float* __restrict__ x, const bf16* __restrict__ msg,
    const bf16* __restrict__ Wo, const bf16* __restrict__ W0, const bf16* __restrict__ W1,
    const bf16* __restrict__ W2,
    const float* __restrict__ b0, const float* __restrict__ b1, const float* __restrict__ b2,
    const float* __restrict__ ngm, const float* __restrict__ nbe,
    float* __restrict__ xout, int N)
{
    __shared__ bf16 cat[4][16][136];
    __shared__ bf16 hbl[4][16][72];
    const int w = threadIdx.x >> 6, lane = threadIdx.x & 63;
    const int nbase = blockIdx.x * 64 + w * 16;
    bf16* catw = &cat[w][0][0];
    bf16* hbw  = &hbl[w][0][0];

    {
        const int r = lane >> 2, q = lane & 3;
        const int nd = min(nbase + r, N - 1);
        const float4* xp = reinterpret_cast<const float4*>(x) + (size_t)nd * 16 + q * 4;
        stash8(catw + r * 136 + q * 16,     xp[0], xp[1]);
        stash8(catw + r * 136 + q * 16 + 8, xp[2], xp[3]);
        const bf16* mp = msg + (size_t)nd * 64 + q * 16;
        *reinterpret_cast<bf16x8*>(hbw + r * 72 + q * 16)     = *reinterpret_cast<const bf16x8*>(mp);
        *reinterpret_cast<bf16x8*>(hbw + r * 72 + q * 16 + 8) = *reinterpret_cast<const bf16x8*>(mp + 8);
    }
    const int g = lane >> 4, c16 = lane & 15;
    f32x4 acc[4];

    mm1s<72, 2>(hbw, 0, Wo, lane, acc);
#pragma unroll
    for (int n = 0; n < 4; ++n)
#pragma unroll
        for (int r = 0; r < 4; ++r)
            catw[(g * 4 + r) * 136 + 64 + n * 16 + c16] = (bf16)acc[n][r];

    mm1s<136, 4>(catw, 0, W0, lane, acc);
    storeh1(hbw, acc, b0, c16, g);
    mm1s<72, 2>(hbw, 0, W1, lane, acc);
    storeh1(hbw, acc, b1, c16, g);
    mm1s<72, 2>(hbw, 0, W2, lane, acc);
#pragma unroll
    for (int n = 0; n < 4; ++n) {
        float bb = b2[n * 16 + c16];
#pragma unroll
        for (int r = 0; r < 4; ++r) acc[n][r] += bb;
    }

    float mu[4], rs[4];
#pragma unroll
    for (int r = 0; r < 4; ++r) {
        float s1 = acc[0][r] + acc[1][r] + acc[2][r] + acc[3][r];
        for (int ms = 1; ms < 16; ms <<= 1) s1 += __shfl_xor(s1, ms);
        float mm = s1 * (1.0f / 64.0f);
        float d0 = acc[0][r] - mm, d1 = acc[1][r] - mm, d2 = acc[2][r] - mm, d3 = acc[3][r] - mm;
        float sq = d0 * d0 + d1 * d1 + d2 * d2 + d3 * d3;
        for (int ms = 1; ms < 16; ms <<= 1) sq += __shfl_xor(sq, ms);
        mu[r] = mm;
        rs[r] = rsqrtf(sq * (1.0f / 64.0f) + 1e-5f);
    }
#pragma unroll
    for (int n = 0; n < 4; ++n) {
        float gg = ngm[n * 16 + c16], bb = nbe[n * 16 + c16];
#pragma unroll
        for (int r = 0; r < 4; ++r) {
            int rowi = g * 4 + r;
            int node = nbase + rowi;
            float v = (acc[n][r] - mu[r]) * rs[r] * gg + bb;
            if (node < N) {
                size_t o = (size_t)node * 64 + n * 16 + c16;
                xout[o] = x[o] + v;
            }
        }
    }
}

// ---------- launcher ----------
extern "C" void kernel_launch(void* const* d_in, const int* in_sizes, int n_in,
                              void* d_out, int out_size, void* d_ws, size_t ws_size,
                              hipStream_t stream)
{
    const float* x   = (const float*)d_in[0];
    const int*   ei  = (const int*)d_in[1];
    const float* ea  = (const float*)d_in[2];
    const float* ew0 = (const float*)d_in[3];
    const float* eb0 = (const float*)d_in[4];
    const float* ew1 = (const float*)d_in[5];
    const float* eb1 = (const float*)d_in[6];
    const float* ew2 = (const float*)d_in[7];
    const float* eb2 = (const float*)d_in[8];
    const float* egm = (const float*)d_in[9];
    const float* ebe = (const float*)d_in[10];
    const float* nw0 = (const float*)d_in[11];
    const float* nb0 = (const float*)d_in[12];
    const float* nw1 = (const float*)d_in[13];
    const float* nb1 = (const float*)d_in[14];
    const float* nw2 = (const float*)d_in[15];
    const float* nb2 = (const float*)d_in[16];
    const float* ngm = (const float*)d_in[17];
    const float* nbe = (const float*)d_in[18];
    const float* wq  = (const float*)d_in[19];
    const float* wk  = (const float*)d_in[20];
    const float* wv  = (const float*)d_in[21];
    const float* wo  = (const float*)d_in[22];

    const int Nn = in_sizes[0] / 64;
    const int Ee = in_sizes[1] / 2;

    char* p = (char*)d_ws;
    auto carve = [&](size_t bytes) {
        char* r = p;
        p += (bytes + 255) & ~(size_t)255;
        return r;
    };
    bf16* W0e = (bf16*)carve(64 * 192 * 2);
    bf16* W1e = (bf16*)carve(64 * 64 * 2);
    bf16* W2e = (bf16*)carve(64 * 64 * 2);
    bf16* Wqb = (bf16*)carve(64 * 64 * 2);
    bf16* Wkb = (bf16*)carve(64 * 64 * 2);
    bf16* Wvb = (bf16*)carve(64 * 64 * 2);
    bf16* Wob = (bf16*)carve(64 * 64 * 2);
    bf16* W0n = (bf16*)carve(64 * 128 * 2);
    bf16* W1n = (bf16*)carve(64 * 64 * 2);
    bf16* W2n = (bf16*)carve(64 * 64 * 2);
    float* scores = (float*)carve((size_t)Ee * 4 * 4);
    bf16*  V      = (bf16*)carve((size_t)Ee * 64 * 2);
    bf16*  msg    = (bf16*)carve((size_t)Nn * 64 * 2);
    bf16*  xb     = (bf16*)carve((size_t)Nn * 64 * 2);
    int*   deg    = (int*)carve((size_t)Nn * 4);
    int*   ofs    = (int*)carve((size_t)Nn * 4);
    int*   cur    = (int*)carve((size_t)Nn * 4);
    int*   eidT   = (int*)carve((size_t)Ee * 4);
    int*   bsum   = (int*)carve(((size_t)Nn / 256 + 2) * 4);

    hipMemsetAsync(deg, 0, (size_t)Nn * 4, stream);
    hipMemsetAsync(cur, 0, (size_t)Nn * 4, stream);

    PrepArgs pa;
    const float* srcs[10] = {ew0, ew1, ew2, wq, wk, wv, wo, nw0, nw1, nw2};
    bf16* dsts[10]        = {W0e, W1e, W2e, Wqb, Wkb, Wvb, Wob, W0n, W1n, W2n};
    const int sizes[10]   = {12288, 4096, 4096, 4096, 4096, 4096, 4096, 8192, 4096, 4096};
    const int ldks[10]    = {192, 64, 64, 64, 64, 64, 64, 128, 64, 64};
    int acc_ofs = 0;
    for (int i = 0; i < 10; ++i) {
        pa.src[i] = srcs[i];
        pa.dst[i] = dsts[i];
        pa.ofs[i] = acc_ofs;
        pa.ldk[i] = ldks[i];
        acc_ofs += sizes[i];
    }
    pa.ofs[10] = acc_ofs;
    const int totalFrag = acc_ofs / 8;
    const int total8 = Nn * 64 / 8;
    const int setupTotal = totalFrag + total8 + Ee;
    setup_kernel<<<(setupTotal + 255) / 256, 256, 0, stream>>>(pa, totalFrag, x, xb, total8,
                                                               ei, deg, Ee);

    // CSR build (for gather)
    const int nb = (Nn + 255) / 256;
    scan1_kernel<<<nb, 256, 0, stream>>>(deg, ofs, bsum, Nn);
    scan2_kernel<<<1, 256, 0, stream>>>(bsum, nb);
    scan3_kernel<<<nb, 256, 0, stream>>>(ofs, bsum, Nn);
    fill_kernel<<<(Ee + 255) / 256, 256, 0, stream>>>(ei, ofs, cur, eidT, Ee);

    float* xout = (float*)d_out;
    float* eout = (float*)d_out + (size_t)Nn * 64;

    // edge MLP + scores + V (T=4 tiles/block, ea async-staged one tile ahead via LDS)
    const int tiles = Ee / 128;
    const int TT = 4;
    const int NB = tiles / TT;
    const int rem = tiles - NB * TT;
    if (NB > 0)
        e1_kernel<4><<<NB, 256, 0, stream>>>(xb, ei, ea, W0e, W1e, W2e, Wqb, Wkb, Wvb,
                                             eb0, eb1, eb2, egm, ebe,
                                             scores, V, eout, 0, Ee);
    if (rem > 0)
        e1_kernel<1><<<rem, 256, 0, stream>>>(xb, ei, ea, W0e, W1e, W2e, Wqb, Wkb, Wvb,
                                              eb0, eb1, eb2, egm, ebe,
                                              scores, V, eout, NB * TT, Ee);

    // per-node softmax-weighted gather (random reads via eidT, L3-served)
    gather_kernel<<<(Nn + 3) / 4, 256, 0, stream>>>(deg, ofs, eidT, scores, V, msg, Nn);

    // node MLP
    n_kernel<<<(Nn + 63) / 64, 256, 0, stream>>>(x, msg, Wob, W0n, W1n, W2n,
                                                 nb0, nb1, nb2, ngm, nbe, xout, Nn);
}

// Round 12
// 762.081 us; speedup vs baseline: 1.0016x; 1.0016x over previous
//
#include <hip/hip_runtime.h>

typedef __bf16 bf16;
typedef __attribute__((ext_vector_type(8))) __bf16 bf16x8;
typedef __attribute__((ext_vector_type(4))) __bf16 bf16x4;
typedef __attribute__((ext_vector_type(4))) float  f32x4;

// ---------- helpers ----------
__device__ __forceinline__ f32x4 mfma16(bf16x8 a, bf16x8 b, f32x4 c) {
    return __builtin_amdgcn_mfma_f32_16x16x32_bf16(a, b, c, 0, 0, 0);
}

__device__ __forceinline__ void stash8(bf16* dst, float4 a, float4 b) {
    bf16x8 v;
    v[0] = (bf16)a.x; v[1] = (bf16)a.y; v[2] = (bf16)a.z; v[3] = (bf16)a.w;
    v[4] = (bf16)b.x; v[5] = (bf16)b.y; v[6] = (bf16)b.z; v[7] = (bf16)b.w;
    *reinterpret_cast<bf16x8*>(dst) = v;
}

// async global->LDS, 16B per lane, zero VGPR cost for the data
__device__ __forceinline__ void glds16(const float* g, float* l) {
    __builtin_amdgcn_global_load_lds((__attribute__((address_space(1))) const void*)g,
                                     (__attribute__((address_space(3))) void*)l, 16, 0, 0);
}

// B-fragment from PRE-SWIZZLED weights: 64 lanes read one contiguous 1KB block.
__device__ __forceinline__ bf16x8 wfrag(const bf16* __restrict__ W, int s, int n, int lane) {
    return *reinterpret_cast<const bf16x8*>(W + (((s * 4 + n) * 64 + lane) * 8));
}

// 2-M-tile x 4-N-tile MFMA matmul; A from LDS (pitch P), B swizzled, KS k-steps.
template<int P, int KS>
__device__ __forceinline__ void mm2s(const bf16* __restrict__ src, int kofs,
                                     const bf16* __restrict__ W,
                                     int lane, f32x4 (&acc)[2][4]) {
    const int c16 = lane & 15, g = lane >> 4;
#pragma unroll
    for (int m = 0; m < 2; ++m)
#pragma unroll
        for (int n = 0; n < 4; ++n) acc[m][n] = 0.0f;
#pragma unroll
    for (int s = 0; s < KS; ++s) {
        bf16x8 aA = *reinterpret_cast<const bf16x8*>(src + c16 * P + kofs + s * 32 + g * 8);
        bf16x8 aB = *reinterpret_cast<const bf16x8*>(src + (16 + c16) * P + kofs + s * 32 + g * 8);
#pragma unroll
        for (int n = 0; n < 4; ++n) {
            bf16x8 bb = wfrag(W, s, n, lane);
            acc[0][n] = mfma16(aA, bb, acc[0][n]);
            acc[1][n] = mfma16(aB, bb, acc[1][n]);
        }
    }
}

template<int P, int KS>
__device__ __forceinline__ void mm1s(const bf16* __restrict__ src, int kofs,
                                     const bf16* __restrict__ W,
                                     int lane, f32x4 (&acc)[4]) {
    const int c16 = lane & 15, g = lane >> 4;
#pragma unroll
    for (int n = 0; n < 4; ++n) acc[n] = 0.0f;
#pragma unroll
    for (int s = 0; s < KS; ++s) {
        bf16x8 a = *reinterpret_cast<const bf16x8*>(src + c16 * P + kofs + s * 32 + g * 8);
#pragma unroll
        for (int n = 0; n < 4; ++n) {
            bf16x8 bb = wfrag(W, s, n, lane);
            acc[n] = mfma16(a, bb, acc[n]);
        }
    }
}

__device__ __forceinline__ void storeh2(bf16* hbw, const f32x4 (&acc)[2][4],
                                        const float* __restrict__ bias, int c16, int g) {
#pragma unroll
    for (int n = 0; n < 4; ++n) {
        float bb = bias[n * 16 + c16];
#pragma unroll
        for (int m = 0; m < 2; ++m)
#pragma unroll
            for (int r = 0; r < 4; ++r)
                hbw[(m * 16 + g * 4 + r) * 72 + n * 16 + c16] = (bf16)fmaxf(acc[m][n][r] + bb, 0.0f);
    }
}

__device__ __forceinline__ void storeh1(bf16* hbw, const f32x4 (&acc)[4],
                                        const float* __restrict__ bias, int c16, int g) {
#pragma unroll
    for (int n = 0; n < 4; ++n) {
        float bb = bias[n * 16 + c16];
#pragma unroll
        for (int r = 0; r < 4; ++r)
            hbw[(g * 4 + r) * 72 + n * 16 + c16] = (bf16)fmaxf(acc[n][r] + bb, 0.0f);
    }
}

// ---------- setup: weight swizzle + x->bf16 copy + degree count (fused) ----------
struct PrepArgs {
    const float* src[10];
    bf16* dst[10];
    int ofs[11];
    int ldk[10];
};

__global__ __launch_bounds__(256) void setup_kernel(PrepArgs a, int totalFrag,
                                                    const float* __restrict__ x,
                                                    bf16* __restrict__ xbuf, int total8,
                                                    const int* __restrict__ ei,
                                                    int* __restrict__ deg, int E) {
    int t = blockIdx.x * 256 + threadIdx.x;
    if (t < totalFrag) {
        int eb = t * 8;
        int k = 0;
        while (k < 9 && eb >= a.ofs[k + 1]) ++k;
        int f = (eb - a.ofs[k]) >> 3;
        int lane = f & 63, n = (f >> 6) & 3, s = f >> 8;
        int c16 = lane & 15, g = lane >> 4;
        const float* sp = a.src[k] + (n * 16 + c16) * a.ldk[k] + s * 32 + g * 8;
        float4 v0 = *reinterpret_cast<const float4*>(sp);
        float4 v1 = *reinterpret_cast<const float4*>(sp + 4);
        stash8(a.dst[k] + (size_t)f * 8, v0, v1);
        return;
    }
    t -= totalFrag;
    if (t < total8) {
        const float4* p = reinterpret_cast<const float4*>(x) + t * 2;
        stash8(xbuf + (size_t)t * 8, p[0], p[1]);
        return;
    }
    t -= total8;
    if (t < E) atomicAdd(&deg[ei[E + t]], 1);
}

// ---------- CSR scan ----------
__global__ __launch_bounds__(256) void scan1_kernel(const int* __restrict__ deg, int* __restrict__ ofs,
                                                    int* __restrict__ bsum, int N) {
    __shared__ int ws4[4];
    const int t = threadIdx.x, lane = t & 63, w = t >> 6;
    const int i = blockIdx.x * 256 + t;
    const int v = (i < N) ? deg[i] : 0;
    int inc = v;
#pragma unroll
    for (int o = 1; o < 64; o <<= 1) { int u = __shfl_up(inc, o); if (lane >= o) inc += u; }
    if (lane == 63) ws4[w] = inc;
    __syncthreads();
    int add = 0;
    for (int k = 0; k < w; ++k) add += ws4[k];
    if (i < N) ofs[i] = inc - v + add;
    if (t == 255) bsum[blockIdx.x] = inc + add;
}

__global__ __launch_bounds__(256) void scan2_kernel(int* __restrict__ bsum, int nb) {
    __shared__ int ws4[4];
    const int t = threadIdx.x, lane = t & 63, w = t >> 6;
    const int v = (t < nb) ? bsum[t] : 0;
    int inc = v;
#pragma unroll
    for (int o = 1; o < 64; o <<= 1) { int u = __shfl_up(inc, o); if (lane >= o) inc += u; }
    if (lane == 63) ws4[w] = inc;
    __syncthreads();
    int add = 0;
    for (int k = 0; k < w; ++k) add += ws4[k];
    if (t < nb) bsum[t] = inc - v + add;
}

__global__ __launch_bounds__(256) void scan3_kernel(int* __restrict__ ofs, const int* __restrict__ bsum, int N) {
    const int i = blockIdx.x * 256 + threadIdx.x;
    if (i < N) ofs[i] += bsum[blockIdx.x];
}

// ---------- CSR fill ----------
__global__ __launch_bounds__(256) void fill_kernel(const int* __restrict__ ei, const int* __restrict__ ofs,
                                                   int* __restrict__ cur, int* __restrict__ eidT, int E) {
    const int e = blockIdx.x * 256 + threadIdx.x;
    if (e >= E) return;
    const int d = ei[E + e];
    const int slot = atomicAdd(&cur[d], 1);
    eidT[ofs[d] + slot] = e;
}

// ---------- E1: r8 body + glds ea prefetch with COUNTED vmcnt (no store drain) ----------
// Invariant: glds issued in tile k-1 have >=85 vmem ops issued after them
// (64 weight loads + 13 stores + 4 ei + 8 x-loads), so s_waitcnt vmcnt(63)
// proves their completion without draining the store queue.
template<int T>
__global__ __launch_bounds__(256, 4) void e1_kernel(
    const bf16* __restrict__ xb, const int* __restrict__ ei, const float* __restrict__ ea,
    const bf16* __restrict__ W0, const bf16* __restrict__ W1, const bf16* __restrict__ W2,
    const bf16* __restrict__ Wq, const bf16* __restrict__ Wk, const bf16* __restrict__ Wv,
    const float* __restrict__ b0, const float* __restrict__ b1, const float* __restrict__ b2,
    const float* __restrict__ egm, const float* __restrict__ ebe,
    float* __restrict__ scoresOut, bf16* __restrict__ Vout, float* __restrict__ eout,
    int tileOfs, int E)
{
    __shared__ float stg[4][2048];    // per-wave async ea staging (8KB, f32, linear)
    __shared__ bf16 eas[4][32][72];   // edge_attr rows (bf16), pitch 72
    __shared__ bf16 hbl[4][32][72];   // inter-layer transpose buffer, pitch 72
    const int w = threadIdx.x >> 6;
    const int lane = threadIdx.x & 63;
    const int g = lane >> 4, c16 = lane & 15;
    const int rr = lane >> 4, cc = (lane & 15) * 4;
    float* stgw = &stg[w][0];
    bf16* eaw = &eas[w][0][0];
    bf16* hbw = &hbl[w][0][0];
    const int tile0 = tileOfs + blockIdx.x * T;

    // ---- prologue: async-stage tile0's ea; load tile0's edge indices
    {
        const size_t gb = (size_t)(tile0 * 128 + w * 32) * 64;
#pragma unroll
        for (int j = 0; j < 8; ++j)
            glds16(ea + gb + j * 256 + lane * 4, stgw + j * 256);
    }
    int dn0, dn1, sn0, sn1;
    {
        const int tb = tile0 * 128 + w * 32;
        dn0 = ei[E + tb + c16]; dn1 = ei[E + tb + 16 + c16];
        sn0 = ei[tb + c16];     sn1 = ei[tb + 16 + c16];
    }

    for (int k = 0; k < T; ++k) {
        const int ebase = (tile0 + k) * 128 + w * 32;

        // ---- issue current tile's x-fragment loads (indices already resident)
        bf16x8 fxd[2][2], fxs[2][2];
#pragma unroll
        for (int s = 0; s < 2; ++s) {
            fxd[0][s] = *reinterpret_cast<const bf16x8*>(xb + (size_t)dn0 * 64 + s * 32 + g * 8);
            fxd[1][s] = *reinterpret_cast<const bf16x8*>(xb + (size_t)dn1 * 64 + s * 32 + g * 8);
            fxs[0][s] = *reinterpret_cast<const bf16x8*>(xb + (size_t)sn0 * 64 + s * 32 + g * 8);
            fxs[1][s] = *reinterpret_cast<const bf16x8*>(xb + (size_t)sn1 * 64 + s * 32 + g * 8);
        }

        // ---- wait for staged ea: counted (k>0) so stores are NOT drained
        if (k == 0) asm volatile("s_waitcnt vmcnt(0)" ::: "memory");
        else        asm volatile("s_waitcnt vmcnt(63)" ::: "memory");
#pragma unroll
        for (int j = 0; j < 8; ++j) {
            int row = j * 4 + rr;
            float4 v = *reinterpret_cast<const float4*>(stgw + row * 64 + cc);
            bf16x4 o;
            o[0] = (bf16)v.x; o[1] = (bf16)v.y; o[2] = (bf16)v.z; o[3] = (bf16)v.w;
            *reinterpret_cast<bf16x4*>(eaw + row * 72 + cc) = o;
        }
        asm volatile("s_waitcnt lgkmcnt(0)" ::: "memory");

        // ---- issue NEXT tile's async ea staging + ei prefetch (in flight all tile)
        int ndn0, ndn1, nsn0, nsn1;
        if (k + 1 < T) {
            const int nb2 = ebase + 128;
            const size_t gb = (size_t)nb2 * 64;
#pragma unroll
            for (int j = 0; j < 8; ++j)
                glds16(ea + gb + j * 256 + lane * 4, stgw + j * 256);
            ndn0 = ei[E + nb2 + c16]; ndn1 = ei[E + nb2 + 16 + c16];
            nsn0 = ei[nb2 + c16];     nsn1 = ei[nb2 + 16 + c16];
            asm volatile("" ::: "memory");   // pin glds early (no full sched pin)
        }

        // ---- Q/K + per-head scores; LDS-staged 512B contiguous store
        {
            f32x4 aq[2][4], ak[2][4];
#pragma unroll
            for (int m = 0; m < 2; ++m)
#pragma unroll
                for (int n = 0; n < 4; ++n) { aq[m][n] = 0.0f; ak[m][n] = 0.0f; }
#pragma unroll
            for (int s = 0; s < 2; ++s)
#pragma unroll
                for (int n = 0; n < 4; ++n) {
                    bf16x8 bq = wfrag(Wq, s, n, lane);
                    bf16x8 bk = wfrag(Wk, s, n, lane);
                    aq[0][n] = mfma16(fxd[0][s], bq, aq[0][n]);
                    aq[1][n] = mfma16(fxd[1][s], bq, aq[1][n]);
                    ak[0][n] = mfma16(fxs[0][s], bk, ak[0][n]);
                    ak[1][n] = mfma16(fxs[1][s], bk, ak[1][n]);
                }
            float* sst = reinterpret_cast<float*>(hbw);
#pragma unroll
            for (int n = 0; n < 4; ++n) {
#pragma unroll
                for (int m = 0; m < 2; ++m) {
                    float pr[4];
#pragma unroll
                    for (int r = 0; r < 4; ++r) pr[r] = aq[m][n][r] * ak[m][n][r];
#pragma unroll
                    for (int ms = 1; ms < 16; ms <<= 1)
#pragma unroll
                        for (int r = 0; r < 4; ++r) pr[r] += __shfl_xor(pr[r], ms);
                    if (c16 == n) {
#pragma unroll
                        for (int r = 0; r < 4; ++r)
                            sst[(m * 16 + g * 4 + r) * 4 + n] = pr[r] * 0.25f;  // / sqrt(16)
                    }
                }
            }
            float2 sv = *reinterpret_cast<const float2*>(sst + lane * 2);
            *reinterpret_cast<float2*>(scoresOut + (size_t)ebase * 4 + lane * 2) = sv;
        }

        // ---- L0: W0 * [xd | xs | ea]  (K = 192)
        f32x4 acc[2][4], acc2[2][4];
#pragma unroll
        for (int m = 0; m < 2; ++m)
#pragma unroll
            for (int n = 0; n < 4; ++n) acc[m][n] = 0.0f;
#pragma unroll
        for (int s = 0; s < 2; ++s)
#pragma unroll
            for (int n = 0; n < 4; ++n) {
                bf16x8 bd = wfrag(W0, s, n, lane);
                acc[0][n] = mfma16(fxd[0][s], bd, acc[0][n]);
                acc[1][n] = mfma16(fxd[1][s], bd, acc[1][n]);
                bf16x8 bs = wfrag(W0, s + 2, n, lane);
                acc[0][n] = mfma16(fxs[0][s], bs, acc[0][n]);
                acc[1][n] = mfma16(fxs[1][s], bs, acc[1][n]);
            }
#pragma unroll
        for (int s = 0; s < 2; ++s) {
            bf16x8 ae0 = *reinterpret_cast<const bf16x8*>(eaw + c16 * 72 + s * 32 + g * 8);
            bf16x8 ae1 = *reinterpret_cast<const bf16x8*>(eaw + (16 + c16) * 72 + s * 32 + g * 8);
#pragma unroll
            for (int n = 0; n < 4; ++n) {
                bf16x8 be = wfrag(W0, s + 4, n, lane);
                acc[0][n] = mfma16(ae0, be, acc[0][n]);
                acc[1][n] = mfma16(ae1, be, acc[1][n]);
            }
        }

        // ---- relu -> L1 -> relu -> L2 + b2
        storeh2(hbw, acc, b0, c16, g);
        mm2s<72, 2>(hbw, 0, W1, lane, acc);
        storeh2(hbw, acc, b1, c16, g);
        mm2s<72, 2>(hbw, 0, W2, lane, acc2);
#pragma unroll
        for (int n = 0; n < 4; ++n) {
            float bb = b2[n * 16 + c16];
#pragma unroll
            for (int m = 0; m < 2; ++m)
#pragma unroll
                for (int r = 0; r < 4; ++r) acc2[m][n][r] += bb;
        }

        // ---- LayerNorm per edge row
        float mu[2][4], rs[2][4];
#pragma unroll
        for (int m = 0; m < 2; ++m)
#pragma unroll
            for (int r = 0; r < 4; ++r) {
                float s1 = acc2[m][0][r] + acc2[m][1][r] + acc2[m][2][r] + acc2[m][3][r];
                for (int ms = 1; ms < 16; ms <<= 1) s1 += __shfl_xor(s1, ms);
                float mm = s1 * (1.0f / 64.0f);
                float d0 = acc2[m][0][r] - mm, d1 = acc2[m][1][r] - mm;
                float d2 = acc2[m][2][r] - mm, d3 = acc2[m][3][r] - mm;
                float sq = d0 * d0 + d1 * d1 + d2 * d2 + d3 * d3;
                for (int ms = 1; ms < 16; ms <<= 1) sq += __shfl_xor(sq, ms);
                mu[m][r] = mm;
                rs[m][r] = rsqrtf(sq * (1.0f / 64.0f) + 1e-5f);
            }

        // ---- e_new -> hbl (A-layout, bf16)
#pragma unroll
        for (int n = 0; n < 4; ++n) {
            float gg = egm[n * 16 + c16], bb = ebe[n * 16 + c16];
#pragma unroll
            for (int m = 0; m < 2; ++m)
#pragma unroll
                for (int r = 0; r < 4; ++r) {
                    int rowi = m * 16 + g * 4 + r;
                    float v = (acc2[m][n][r] - mu[m][r]) * rs[m][r] * gg + bb;
                    hbw[rowi * 72 + n * 16 + c16] = (bf16)v;
                }
        }

        // ---- eout = edge_attr + e_new; 1KB-contiguous stores
#pragma unroll
        for (int i = 0; i < 8; ++i) {
            int row = i * 4 + rr;
            bf16x4 hv = *reinterpret_cast<const bf16x4*>(hbw + row * 72 + cc);
            bf16x4 av = *reinterpret_cast<const bf16x4*>(eaw + row * 72 + cc);
            float4 o;
            o.x = (float)av[0] + (float)hv[0];
            o.y = (float)av[1] + (float)hv[1];
            o.z = (float)av[2] + (float)hv[2];
            o.w = (float)av[3] + (float)hv[3];
            *reinterpret_cast<float4*>(eout + (size_t)(ebase + row) * 64 + cc) = o;
        }

        // ---- V = e_new @ wv.T ; 1KB-contiguous stores (stages into eaw, now dead)
        mm2s<72, 2>(hbw, 0, Wv, lane, acc);
#pragma unroll
        for (int n = 0; n < 4; ++n)
#pragma unroll
            for (int m = 0; m < 2; ++m)
#pragma unroll
                for (int r = 0; r < 4; ++r)
                    eaw[(m * 16 + g * 4 + r) * 72 + n * 16 + c16] = (bf16)acc[m][n][r];
#pragma unroll
        for (int kk = 0; kk < 4; ++kk) {
            int row = kk * 8 + (lane >> 3);
            int col = (lane & 7) * 8;
            bf16x8 v = *reinterpret_cast<const bf16x8*>(eaw + row * 72 + col);
            *reinterpret_cast<bf16x8*>(Vout + (size_t)(ebase + row) * 64 + col) = v;
        }

        if (k + 1 < T) { dn0 = ndn0; dn1 = ndn1; sn0 = nsn0; sn1 = nsn1; }
    }
}

// ---------- gather: per-node online softmax; V/scores via eidT (random reads, L3) ----------
__global__ __launch_bounds__(256) void gather_kernel(
    const int* __restrict__ deg, const int* __restrict__ ofs, const int* __restrict__ eidT,
    const float* __restrict__ scores, const bf16* __restrict__ V,
    bf16* __restrict__ msg, int N)
{
    const int w = threadIdx.x >> 6, lane = threadIdx.x & 63;
    const int n = blockIdx.x * 4 + w;
    if (n >= N) return;
    const int cnt = deg[n];
    const int* lst = eidT + ofs[n];
    const int h = lane >> 4;
    float m = -3.4e38f, s = 0.f, acc = 0.f;

    int eA = (lane < cnt) ? lst[lane] : 0;
    int eB = (64 + lane < cnt) ? lst[64 + lane] : 0;
    const int nr = min(cnt, 128);
    if (nr > 0) {
        int e = __shfl(eA, 0);
        float sc = scores[(size_t)e * 4 + h];
        float v  = (float)V[(size_t)e * 64 + lane];
        for (int i = 1; i <= nr; ++i) {
            float sc2 = 0.f, v2 = 0.f;
            if (i < nr) {
                int e2 = __shfl((i < 64) ? eA : eB, i & 63);
                sc2 = scores[(size_t)e2 * 4 + h];
                v2  = (float)V[(size_t)e2 * 64 + lane];
            }
            float mn = fmaxf(m, sc);
            float c  = __expf(m - mn);
            float ex = __expf(sc - mn);
            s = s * c + ex;
            acc = acc * c + ex * v;
            m = mn;
            sc = sc2; v = v2;
        }
    }
    for (int i = 128; i < cnt; ++i) {
        int e = lst[i];
        float sc = scores[(size_t)e * 4 + h];
        float v  = (float)V[(size_t)e * 64 + lane];
        float mn = fmaxf(m, sc);
        float c  = __expf(m - mn);
        float ex = __expf(sc - mn);
        s = s * c + ex;
        acc = acc * c + ex * v;
        m = mn;
    }
    msg[(size_t)n * 64 + lane] = (bf16)(acc / (s + 1e-12f));
}

// ---------- N: node MLP ----------
__global__ __launch_bounds__(256, 4) void n_kernel(
    const float* __restrict__ x, const bf16* __restrict__ msg,
    const bf16* __restrict__ Wo, const bf16* __restrict__ W0, const bf16* __restrict__ W1,
    const bf16* __restrict__ W2,
    const float* __restrict__ b0, const float* __restrict__ b1, const float* __restrict__ b2,
    const float* __restrict__ ngm, const float* __restrict__ nbe,
    float* __restrict__ xout, int N)
{
    __shared__ bf16 cat[4][16][136];
    __shared__ bf16 hbl[4][16][72];
    const int w = threadIdx.x >> 6, lane = threadIdx.x & 63;
    const int nbase = blockIdx.x * 64 + w * 16;
    bf16* catw = &cat[w][0][0];
    bf16* hbw  = &hbl[w][0][0];

    {
        const int r = lane >> 2, q = lane & 3;
        const int nd = min(nbase + r, N - 1);
        const float4* xp = reinterpret_cast<const float4*>(x) + (size_t)nd * 16 + q * 4;
        stash8(catw + r * 136 + q * 16,     xp[0], xp[1]);
        stash8(catw + r * 136 + q * 16 + 8, xp[2], xp[3]);
        const bf16* mp = msg + (size_t)nd * 64 + q * 16;
        *reinterpret_cast<bf16x8*>(hbw + r * 72 + q * 16)     = *reinterpret_cast<const bf16x8*>(mp);
        *reinterpret_cast<bf16x8*>(hbw + r * 72 + q * 16 + 8) = *reinterpret_cast<const bf16x8*>(mp + 8);
    }
    const int g = lane >> 4, c16 = lane & 15;
    f32x4 acc[4];

    mm1s<72, 2>(hbw, 0, Wo, lane, acc);
#pragma unroll
    for (int n = 0; n < 4; ++n)
#pragma unroll
        for (int r = 0; r < 4; ++r)
            catw[(g * 4 + r) * 136 + 64 + n * 16 + c16] = (bf16)acc[n][r];

    mm1s<136, 4>(catw, 0, W0, lane, acc);
    storeh1(hbw, acc, b0, c16, g);
    mm1s<72, 2>(hbw, 0, W1, lane, acc);
    storeh1(hbw, acc, b1, c16, g);
    mm1s<72, 2>(hbw, 0, W2, lane, acc);
#pragma unroll
    for (int n = 0; n < 4; ++n) {
        float bb = b2[n * 16 + c16];
#pragma unroll
        for (int r = 0; r < 4; ++r) acc[n][r] += bb;
    }

    float mu[4], rs[4];
#pragma unroll
    for (int r = 0; r < 4; ++r) {
        float s1 = acc[0][r] + acc[1][r] + acc[2][r] + acc[3][r];
        for (int ms = 1; ms < 16; ms <<= 1) s1 += __shfl_xor(s1, ms);
        float mm = s1 * (1.0f / 64.0f);
        float d0 = acc[0][r] - mm, d1 = acc[1][r] - mm, d2 = acc[2][r] - mm, d3 = acc[3][r] - mm;
        float sq = d0 * d0 + d1 * d1 + d2 * d2 + d3 * d3;
        for (int ms = 1; ms < 16; ms <<= 1) sq += __shfl_xor(sq, ms);
        mu[r] = mm;
        rs[r] = rsqrtf(sq * (1.0f / 64.0f) + 1e-5f);
    }
#pragma unroll
    for (int n = 0; n < 4; ++n) {
        float gg = ngm[n * 16 + c16], bb = nbe[n * 16 + c16];
#pragma unroll
        for (int r = 0; r < 4; ++r) {
            int rowi = g * 4 + r;
            int node = nbase + rowi;
            float v = (acc[n][r] - mu[r]) * rs[r] * gg + bb;
            if (node < N) {
                size_t o = (size_t)node * 64 + n * 16 + c16;
                xout[o] = x[o] + v;
            }
        }
    }
}

// ---------- launcher ----------
extern "C" void kernel_launch(void* const* d_in, const int* in_sizes, int n_in,
                              void* d_out, int out_size, void* d_ws, size_t ws_size,
                              hipStream_t stream)
{
    const float* x   = (const float*)d_in[0];
    const int*   ei  = (const int*)d_in[1];
    const float* ea  = (const float*)d_in[2];
    const float* ew0 = (const float*)d_in[3];
    const float* eb0 = (const float*)d_in[4];
    const float* ew1 = (const float*)d_in[5];
    const float* eb1 = (const float*)d_in[6];
    const float* ew2 = (const float*)d_in[7];
    const float* eb2 = (const float*)d_in[8];
    const float* egm = (const float*)d_in[9];
    const float* ebe = (const float*)d_in[10];
    const float* nw0 = (const float*)d_in[11];
    const float* nb0 = (const float*)d_in[12];
    const float* nw1 = (const float*)d_in[13];
    const float* nb1 = (const float*)d_in[14];
    const float* nw2 = (const float*)d_in[15];
    const float* nb2 = (const float*)d_in[16];
    const float* ngm = (const float*)d_in[17];
    const float* nbe = (const float*)d_in[18];
    const float* wq  = (const float*)d_in[19];
    const float* wk  = (const float*)d_in[20];
    const float* wv  = (const float*)d_in[21];
    const float* wo  = (const float*)d_in[22];

    const int Nn = in_sizes[0] / 64;
    const int Ee = in_sizes[1] / 2;

    char* p = (char*)d_ws;
    auto carve = [&](size_t bytes) {
        char* r = p;
        p += (bytes + 255) & ~(size_t)255;
        return r;
    };
    bf16* W0e = (bf16*)carve(64 * 192 * 2);
    bf16* W1e = (bf16*)carve(64 * 64 * 2);
    bf16* W2e = (bf16*)carve(64 * 64 * 2);
    bf16* Wqb = (bf16*)carve(64 * 64 * 2);
    bf16* Wkb = (bf16*)carve(64 * 64 * 2);
    bf16* Wvb = (bf16*)carve(64 * 64 * 2);
    bf16* Wob = (bf16*)carve(64 * 64 * 2);
    bf16* W0n = (bf16*)carve(64 * 128 * 2);
    bf16* W1n = (bf16*)carve(64 * 64 * 2);
    bf16* W2n = (bf16*)carve(64 * 64 * 2);
    float* scores = (float*)carve((size_t)Ee * 4 * 4);
    bf16*  V      = (bf16*)carve((size_t)Ee * 64 * 2);
    bf16*  msg    = (bf16*)carve((size_t)Nn * 64 * 2);
    bf16*  xb     = (bf16*)carve((size_t)Nn * 64 * 2);
    int*   deg    = (int*)carve((size_t)Nn * 4);
    int*   ofs    = (int*)carve((size_t)Nn * 4);
    int*   cur    = (int*)carve((size_t)Nn * 4);
    int*   eidT   = (int*)carve((size_t)Ee * 4);
    int*   bsum   = (int*)carve(((size_t)Nn / 256 + 2) * 4);

    hipMemsetAsync(deg, 0, (size_t)Nn * 4, stream);
    hipMemsetAsync(cur, 0, (size_t)Nn * 4, stream);

    PrepArgs pa;
    const float* srcs[10] = {ew0, ew1, ew2, wq, wk, wv, wo, nw0, nw1, nw2};
    bf16* dsts[10]        = {W0e, W1e, W2e, Wqb, Wkb, Wvb, Wob, W0n, W1n, W2n};
    const int sizes[10]   = {12288, 4096, 4096, 4096, 4096, 4096, 4096, 8192, 4096, 4096};
    const int ldks[10]    = {192, 64, 64, 64, 64, 64, 64, 128, 64, 64};
    int acc_ofs = 0;
    for (int i = 0; i < 10; ++i) {
        pa.src[i] = srcs[i];
        pa.dst[i] = dsts[i];
        pa.ofs[i] = acc_ofs;
        pa.ldk[i] = ldks[i];
        acc_ofs += sizes[i];
    }
    pa.ofs[10] = acc_ofs;
    const int totalFrag = acc_ofs / 8;
    const int total8 = Nn * 64 / 8;
    const int setupTotal = totalFrag + total8 + Ee;
    setup_kernel<<<(setupTotal + 255) / 256, 256, 0, stream>>>(pa, totalFrag, x, xb, total8,
                                                               ei, deg, Ee);

    // CSR build (for gather)
    const int nb = (Nn + 255) / 256;
    scan1_kernel<<<nb, 256, 0, stream>>>(deg, ofs, bsum, Nn);
    scan2_kernel<<<1, 256, 0, stream>>>(bsum, nb);
    scan3_kernel<<<nb, 256, 0, stream>>>(ofs, bsum, Nn);
    fill_kernel<<<(Ee + 255) / 256, 256, 0, stream>>>(ei, ofs, cur, eidT, Ee);

    float* xout = (float*)d_out;
    float* eout = (float*)d_out + (size_t)Nn * 64;

    // edge MLP + scores + V (T=4 tiles/block, ea async-staged one tile ahead)
    const int tiles = Ee / 128;
    const int TT = 4;
    const int NB = tiles / TT;
    const int rem = tiles - NB * TT;
    if (NB > 0)
        e1_kernel<4><<<NB, 256, 0, stream>>>(xb, ei, ea, W0e, W1e, W2e, Wqb, Wkb, Wvb,
                                             eb0, eb1, eb2, egm, ebe,
                                             scores, V, eout, 0, Ee);
    if (rem > 0)
        e1_kernel<1><<<rem, 256, 0, stream>>>(xb, ei, ea, W0e, W1e, W2e, Wqb, Wkb, Wvb,
                                              eb0, eb1, eb2, egm, ebe,
                                              scores, V, eout, NB * TT, Ee);

    // per-node softmax-weighted gather (random reads via eidT, L3-served)
    gather_kernel<<<(Nn + 3) / 4, 256, 0, stream>>>(deg, ofs, eidT, scores, V, msg, Nn);

    // node MLP
    n_kernel<<<(Nn + 63) / 64, 256, 0, stream>>>(x, msg, Wob, W0n, W1n, W2n,
                                                 nb0, nb1, nb2, ngm, nbe, xout, Nn);
}

// Round 13
// 396.475 us; speedup vs baseline: 1.9253x; 1.9221x over previous
//
#include <hip/hip_runtime.h>

typedef __bf16 bf16;
typedef __attribute__((ext_vector_type(8))) __bf16 bf16x8;
typedef __attribute__((ext_vector_type(4))) __bf16 bf16x4;
typedef __attribute__((ext_vector_type(2))) __bf16 bf16x2;
typedef __attribute__((ext_vector_type(4))) float  f32x4;

// ---------- helpers ----------
__device__ __forceinline__ f32x4 mfma16(bf16x8 a, bf16x8 b, f32x4 c) {
    return __builtin_amdgcn_mfma_f32_16x16x32_bf16(a, b, c, 0, 0, 0);
}

__device__ __forceinline__ void stash8(bf16* dst, float4 a, float4 b) {
    bf16x8 v;
    v[0] = (bf16)a.x; v[1] = (bf16)a.y; v[2] = (bf16)a.z; v[3] = (bf16)a.w;
    v[4] = (bf16)b.x; v[5] = (bf16)b.y; v[6] = (bf16)b.z; v[7] = (bf16)b.w;
    *reinterpret_cast<bf16x8*>(dst) = v;
}

// B-fragment from PRE-SWIZZLED weights: 64 lanes read one contiguous 1KB block.
__device__ __forceinline__ bf16x8 wfrag(const bf16* __restrict__ W, int s, int n, int lane) {
    return *reinterpret_cast<const bf16x8*>(W + (((s * 4 + n) * 64 + lane) * 8));
}

// 2-M-tile x 4-N-tile MFMA matmul; A from LDS (pitch P), B swizzled, KS k-steps.
template<int P, int KS>
__device__ __forceinline__ void mm2s(const bf16* __restrict__ src, int kofs,
                                     const bf16* __restrict__ W,
                                     int lane, f32x4 (&acc)[2][4]) {
    const int c16 = lane & 15, g = lane >> 4;
#pragma unroll
    for (int m = 0; m < 2; ++m)
#pragma unroll
        for (int n = 0; n < 4; ++n) acc[m][n] = 0.0f;
#pragma unroll
    for (int s = 0; s < KS; ++s) {
        bf16x8 aA = *reinterpret_cast<const bf16x8*>(src + c16 * P + kofs + s * 32 + g * 8);
        bf16x8 aB = *reinterpret_cast<const bf16x8*>(src + (16 + c16) * P + kofs + s * 32 + g * 8);
#pragma unroll
        for (int n = 0; n < 4; ++n) {
            bf16x8 bb = wfrag(W, s, n, lane);
            acc[0][n] = mfma16(aA, bb, acc[0][n]);
            acc[1][n] = mfma16(aB, bb, acc[1][n]);
        }
    }
}

template<int P, int KS>
__device__ __forceinline__ void mm1s(const bf16* __restrict__ src, int kofs,
                                     const bf16* __restrict__ W,
                                     int lane, f32x4 (&acc)[4]) {
    const int c16 = lane & 15, g = lane >> 4;
#pragma unroll
    for (int n = 0; n < 4; ++n) acc[n] = 0.0f;
#pragma unroll
    for (int s = 0; s < KS; ++s) {
        bf16x8 a = *reinterpret_cast<const bf16x8*>(src + c16 * P + kofs + s * 32 + g * 8);
#pragma unroll
        for (int n = 0; n < 4; ++n) {
            bf16x8 bb = wfrag(W, s, n, lane);
            acc[n] = mfma16(a, bb, acc[n]);
        }
    }
}

__device__ __forceinline__ void storeh2(bf16* hbw, const f32x4 (&acc)[2][4],
                                        const float* __restrict__ bias, int c16, int g) {
#pragma unroll
    for (int n = 0; n < 4; ++n) {
        float bb = bias[n * 16 + c16];
#pragma unroll
        for (int m = 0; m < 2; ++m)
#pragma unroll
            for (int r = 0; r < 4; ++r)
                hbw[(m * 16 + g * 4 + r) * 72 + n * 16 + c16] = (bf16)fmaxf(acc[m][n][r] + bb, 0.0f);
    }
}

__device__ __forceinline__ void storeh1(bf16* hbw, const f32x4 (&acc)[4],
                                        const float* __restrict__ bias, int c16, int g) {
#pragma unroll
    for (int n = 0; n < 4; ++n) {
        float bb = bias[n * 16 + c16];
#pragma unroll
        for (int r = 0; r < 4; ++r)
            hbw[(g * 4 + r) * 72 + n * 16 + c16] = (bf16)fmaxf(acc[n][r] + bb, 0.0f);
    }
}

// ---------- setup: weight swizzle + x->bf16 copy + degree count (fused) ----------
struct PrepArgs {
    const float* src[10];
    bf16* dst[10];
    int ofs[11];
    int ldk[10];
};

__global__ __launch_bounds__(256) void setup_kernel(PrepArgs a, int totalFrag,
                                                    const float* __restrict__ x,
                                                    bf16* __restrict__ xbuf, int total8,
                                                    const int* __restrict__ ei,
                                                    int* __restrict__ deg, int E) {
    int t = blockIdx.x * 256 + threadIdx.x;
    if (t < totalFrag) {
        int eb = t * 8;
        int k = 0;
        while (k < 9 && eb >= a.ofs[k + 1]) ++k;
        int f = (eb - a.ofs[k]) >> 3;
        int lane = f & 63, n = (f >> 6) & 3, s = f >> 8;
        int c16 = lane & 15, g = lane >> 4;
        const float* sp = a.src[k] + (n * 16 + c16) * a.ldk[k] + s * 32 + g * 8;
        float4 v0 = *reinterpret_cast<const float4*>(sp);
        float4 v1 = *reinterpret_cast<const float4*>(sp + 4);
        stash8(a.dst[k] + (size_t)f * 8, v0, v1);
        return;
    }
    t -= totalFrag;
    if (t < total8) {
        const float4* p = reinterpret_cast<const float4*>(x) + t * 2;
        stash8(xbuf + (size_t)t * 8, p[0], p[1]);
        return;
    }
    t -= total8;
    if (t < E) atomicAdd(&deg[ei[E + t]], 1);
}

// ---------- CSR scan ----------
__global__ __launch_bounds__(256) void scan1_kernel(const int* __restrict__ deg, int* __restrict__ ofs,
                                                    int* __restrict__ bsum, int N) {
    __shared__ int ws4[4];
    const int t = threadIdx.x, lane = t & 63, w = t >> 6;
    const int i = blockIdx.x * 256 + t;
    const int v = (i < N) ? deg[i] : 0;
    int inc = v;
#pragma unroll
    for (int o = 1; o < 64; o <<= 1) { int u = __shfl_up(inc, o); if (lane >= o) inc += u; }
    if (lane == 63) ws4[w] = inc;
    __syncthreads();
    int add = 0;
    for (int k = 0; k < w; ++k) add += ws4[k];
    if (i < N) ofs[i] = inc - v + add;
    if (t == 255) bsum[blockIdx.x] = inc + add;
}

__global__ __launch_bounds__(256) void scan2_kernel(int* __restrict__ bsum, int nb) {
    __shared__ int ws4[4];
    const int t = threadIdx.x, lane = t & 63, w = t >> 6;
    const int v = (t < nb) ? bsum[t] : 0;
    int inc = v;
#pragma unroll
    for (int o = 1; o < 64; o <<= 1) { int u = __shfl_up(inc, o); if (lane >= o) inc += u; }
    if (lane == 63) ws4[w] = inc;
    __syncthreads();
    int add = 0;
    for (int k = 0; k < w; ++k) add += ws4[k];
    if (t < nb) bsum[t] = inc - v + add;
}

// scan3 also zeroes `cur` (folds the second memset into this pass)
__global__ __launch_bounds__(256) void scan3_kernel(int* __restrict__ ofs, const int* __restrict__ bsum,
                                                    int* __restrict__ cur, int N) {
    const int i = blockIdx.x * 256 + threadIdx.x;
    if (i < N) {
        ofs[i] += bsum[blockIdx.x];
        cur[i] = 0;
    }
}

// ---------- CSR fill ----------
__global__ __launch_bounds__(256) void fill_kernel(const int* __restrict__ ei, const int* __restrict__ ofs,
                                                   int* __restrict__ cur, int* __restrict__ eidT, int E) {
    const int e = blockIdx.x * 256 + threadIdx.x;
    if (e >= E) return;
    const int d = ei[E + e];
    const int slot = atomicAdd(&cur[d], 1);
    eidT[ofs[d] + slot] = e;
}

// ---------- E1 (r8-exact body): edge MLP + QKV + scores(bf16) ----------
// All global access instructions are LANE-CONTIGUOUS: ea reads 1KB/instr,
// eout stores 1KB/instr, V stores 1KB/instr, scores 256B/instr (LDS-staged).
__global__ __launch_bounds__(256, 4) void e1_kernel(
    const bf16* __restrict__ xb, const int* __restrict__ ei, const float* __restrict__ ea,
    const bf16* __restrict__ W0, const bf16* __restrict__ W1, const bf16* __restrict__ W2,
    const bf16* __restrict__ Wq, const bf16* __restrict__ Wk, const bf16* __restrict__ Wv,
    const float* __restrict__ b0, const float* __restrict__ b1, const float* __restrict__ b2,
    const float* __restrict__ egm, const float* __restrict__ ebe,
    bf16* __restrict__ scoresOut, bf16* __restrict__ Vout, float* __restrict__ eout, int E)
{
    __shared__ bf16 eas[4][32][72];   // edge_attr rows (bf16), pitch 72
    __shared__ bf16 hbl[4][32][72];   // inter-layer transpose buffer, pitch 72
    const int w = threadIdx.x >> 6;
    const int lane = threadIdx.x & 63;
    const int ebase = blockIdx.x * 128 + w * 32;
    bf16* eaw = &eas[w][0][0];
    bf16* hbw = &hbl[w][0][0];
    const int g = lane >> 4, c16 = lane & 15;

    // ---- stage edge_attr -> LDS bf16; each read instruction = 1KB contiguous
    {
        const int rr = lane >> 4;          // 0..3
        const int cc = (lane & 15) * 4;    // 0..60
#pragma unroll
        for (int i = 0; i < 8; ++i) {
            int row = i * 4 + rr;
            float4 v = *reinterpret_cast<const float4*>(ea + (size_t)(ebase + row) * 64 + cc);
            bf16x4 o;
            o[0] = (bf16)v.x; o[1] = (bf16)v.y; o[2] = (bf16)v.z; o[3] = (bf16)v.w;
            *reinterpret_cast<bf16x4*>(eaw + row * 72 + cc) = o;
        }
    }

    // ---- direct A-fragment loads of x_dst / x_src from bf16 x (L3-resident)
    const int eA0 = ebase + c16, eA1 = ebase + 16 + c16;
    const int dn0 = ei[E + eA0], dn1 = ei[E + eA1];
    const int sn0 = ei[eA0],     sn1 = ei[eA1];
    const bf16* xd0 = xb + (size_t)dn0 * 64;
    const bf16* xd1 = xb + (size_t)dn1 * 64;
    const bf16* xs0 = xb + (size_t)sn0 * 64;
    const bf16* xs1 = xb + (size_t)sn1 * 64;
    bf16x8 fxd[2][2], fxs[2][2];
#pragma unroll
    for (int s = 0; s < 2; ++s) {
        fxd[0][s] = *reinterpret_cast<const bf16x8*>(xd0 + s * 32 + g * 8);
        fxd[1][s] = *reinterpret_cast<const bf16x8*>(xd1 + s * 32 + g * 8);
        fxs[0][s] = *reinterpret_cast<const bf16x8*>(xs0 + s * 32 + g * 8);
        fxs[1][s] = *reinterpret_cast<const bf16x8*>(xs1 + s * 32 + g * 8);
    }

    // ---- Q/K + per-head scores; stage in LDS, 256B contiguous bf16 store
    {
        f32x4 aq[2][4], ak[2][4];
#pragma unroll
        for (int m = 0; m < 2; ++m)
#pragma unroll
            for (int n = 0; n < 4; ++n) { aq[m][n] = 0.0f; ak[m][n] = 0.0f; }
#pragma unroll
        for (int s = 0; s < 2; ++s)
#pragma unroll
            for (int n = 0; n < 4; ++n) {
                bf16x8 bq = wfrag(Wq, s, n, lane);
                bf16x8 bk = wfrag(Wk, s, n, lane);
                aq[0][n] = mfma16(fxd[0][s], bq, aq[0][n]);
                aq[1][n] = mfma16(fxd[1][s], bq, aq[1][n]);
                ak[0][n] = mfma16(fxs[0][s], bk, ak[0][n]);
                ak[1][n] = mfma16(fxs[1][s], bk, ak[1][n]);
            }
        float* sst = reinterpret_cast<float*>(hbw);  // 512B scratch (pre-L0)
#pragma unroll
        for (int n = 0; n < 4; ++n) {
#pragma unroll
            for (int m = 0; m < 2; ++m) {
                float pr[4];
#pragma unroll
                for (int r = 0; r < 4; ++r) pr[r] = aq[m][n][r] * ak[m][n][r];
#pragma unroll
                for (int ms = 1; ms < 16; ms <<= 1)
#pragma unroll
                    for (int r = 0; r < 4; ++r) pr[r] += __shfl_xor(pr[r], ms);
                if (c16 == n) {
#pragma unroll
                    for (int r = 0; r < 4; ++r)
                        sst[(m * 16 + g * 4 + r) * 4 + n] = pr[r] * 0.25f;  // / sqrt(16)
                }
            }
        }
        // one 64-lane x bf16x2 = 256B contiguous store
        float2 sv = *reinterpret_cast<const float2*>(sst + lane * 2);
        bf16x2 so;
        so[0] = (bf16)sv.x; so[1] = (bf16)sv.y;
        *reinterpret_cast<bf16x2*>(scoresOut + (size_t)ebase * 4 + lane * 2) = so;
    }

    // ---- L0: W0 * [xd | xs | ea]  (K = 192)
    f32x4 acc[2][4], acc2[2][4];
#pragma unroll
    for (int m = 0; m < 2; ++m)
#pragma unroll
        for (int n = 0; n < 4; ++n) acc[m][n] = 0.0f;
#pragma unroll
    for (int s = 0; s < 2; ++s)
#pragma unroll
        for (int n = 0; n < 4; ++n) {
            bf16x8 bd = wfrag(W0, s, n, lane);
            acc[0][n] = mfma16(fxd[0][s], bd, acc[0][n]);
            acc[1][n] = mfma16(fxd[1][s], bd, acc[1][n]);
            bf16x8 bs = wfrag(W0, s + 2, n, lane);
            acc[0][n] = mfma16(fxs[0][s], bs, acc[0][n]);
            acc[1][n] = mfma16(fxs[1][s], bs, acc[1][n]);
        }
#pragma unroll
    for (int s = 0; s < 2; ++s) {
        bf16x8 ae0 = *reinterpret_cast<const bf16x8*>(eaw + c16 * 72 + s * 32 + g * 8);
        bf16x8 ae1 = *reinterpret_cast<const bf16x8*>(eaw + (16 + c16) * 72 + s * 32 + g * 8);
#pragma unroll
        for (int n = 0; n < 4; ++n) {
            bf16x8 be = wfrag(W0, s + 4, n, lane);
            acc[0][n] = mfma16(ae0, be, acc[0][n]);
            acc[1][n] = mfma16(ae1, be, acc[1][n]);
        }
    }

    // ---- relu -> L1 -> relu -> L2 + b2
    storeh2(hbw, acc, b0, c16, g);
    mm2s<72, 2>(hbw, 0, W1, lane, acc);
    storeh2(hbw, acc, b1, c16, g);
    mm2s<72, 2>(hbw, 0, W2, lane, acc2);
#pragma unroll
    for (int n = 0; n < 4; ++n) {
        float bb = b2[n * 16 + c16];
#pragma unroll
        for (int m = 0; m < 2; ++m)
#pragma unroll
            for (int r = 0; r < 4; ++r) acc2[m][n][r] += bb;
    }

    // ---- LayerNorm per edge row
    float mu[2][4], rs[2][4];
#pragma unroll
    for (int m = 0; m < 2; ++m)
#pragma unroll
        for (int r = 0; r < 4; ++r) {
            float s1 = acc2[m][0][r] + acc2[m][1][r] + acc2[m][2][r] + acc2[m][3][r];
            for (int ms = 1; ms < 16; ms <<= 1) s1 += __shfl_xor(s1, ms);
            float mm = s1 * (1.0f / 64.0f);
            float d0 = acc2[m][0][r] - mm, d1 = acc2[m][1][r] - mm;
            float d2 = acc2[m][2][r] - mm, d3 = acc2[m][3][r] - mm;
            float sq = d0 * d0 + d1 * d1 + d2 * d2 + d3 * d3;
            for (int ms = 1; ms < 16; ms <<= 1) sq += __shfl_xor(sq, ms);
            mu[m][r] = mm;
            rs[m][r] = rsqrtf(sq * (1.0f / 64.0f) + 1e-5f);
        }

    // ---- e_new -> hbl (A-layout, bf16)
#pragma unroll
    for (int n = 0; n < 4; ++n) {
        float gg = egm[n * 16 + c16], bb = ebe[n * 16 + c16];
#pragma unroll
        for (int m = 0; m < 2; ++m)
#pragma unroll
            for (int r = 0; r < 4; ++r) {
                int rowi = m * 16 + g * 4 + r;
                float v = (acc2[m][n][r] - mu[m][r]) * rs[m][r] * gg + bb;
                hbw[rowi * 72 + n * 16 + c16] = (bf16)v;
            }
    }

    // ---- eout = edge_attr + e_new; each store instruction = 1KB contiguous
    {
        const int rr = lane >> 4;          // 0..3
        const int cc = (lane & 15) * 4;    // 0..60
#pragma unroll
        for (int i = 0; i < 8; ++i) {
            int row = i * 4 + rr;
            bf16x4 hv = *reinterpret_cast<const bf16x4*>(hbw + row * 72 + cc);
            bf16x4 av = *reinterpret_cast<const bf16x4*>(eaw + row * 72 + cc);
            float4 o;
            o.x = (float)av[0] + (float)hv[0];
            o.y = (float)av[1] + (float)hv[1];
            o.z = (float)av[2] + (float)hv[2];
            o.w = (float)av[3] + (float)hv[3];
            *reinterpret_cast<float4*>(eout + (size_t)(ebase + row) * 64 + cc) = o;
        }
    }

    // ---- V = e_new @ wv.T ; 1KB-contiguous stores
    mm2s<72, 2>(hbw, 0, Wv, lane, acc);
#pragma unroll
    for (int n = 0; n < 4; ++n)
#pragma unroll
        for (int m = 0; m < 2; ++m)
#pragma unroll
            for (int r = 0; r < 4; ++r)
                eaw[(m * 16 + g * 4 + r) * 72 + n * 16 + c16] = (bf16)acc[m][n][r];
#pragma unroll
    for (int k = 0; k < 4; ++k) {
        int row = k * 8 + (lane >> 3);
        int col = (lane & 7) * 8;
        bf16x8 v = *reinterpret_cast<const bf16x8*>(eaw + row * 72 + col);
        *reinterpret_cast<bf16x8*>(Vout + (size_t)(ebase + row) * 64 + col) = v;
    }
}

// ---------- gather: per-node online softmax; V/scores via eidT (random reads, L3) ----------
__global__ __launch_bounds__(256) void gather_kernel(
    const int* __restrict__ deg, const int* __restrict__ ofs, const int* __restrict__ eidT,
    const bf16* __restrict__ scores, const bf16* __restrict__ V,
    bf16* __restrict__ msg, int N)
{
    const int w = threadIdx.x >> 6, lane = threadIdx.x & 63;
    const int n = blockIdx.x * 4 + w;
    if (n >= N) return;
    const int cnt = deg[n];
    const int* lst = eidT + ofs[n];
    const int h = lane >> 4;
    float m = -3.4e38f, s = 0.f, acc = 0.f;

    int eA = (lane < cnt) ? lst[lane] : 0;
    int eB = (64 + lane < cnt) ? lst[64 + lane] : 0;
    const int nr = min(cnt, 128);
    if (nr > 0) {
        int e = __shfl(eA, 0);
        float sc = (float)scores[(size_t)e * 4 + h];
        float v  = (float)V[(size_t)e * 64 + lane];
        for (int i = 1; i <= nr; ++i) {
            float sc2 = 0.f, v2 = 0.f;
            if (i < nr) {
                int e2 = __shfl((i < 64) ? eA : eB, i & 63);
                sc2 = (float)scores[(size_t)e2 * 4 + h];
                v2  = (float)V[(size_t)e2 * 64 + lane];
            }
            float mn = fmaxf(m, sc);
            float c  = __expf(m - mn);
            float ex = __expf(sc - mn);
            s = s * c + ex;
            acc = acc * c + ex * v;
            m = mn;
            sc = sc2; v = v2;
        }
    }
    for (int i = 128; i < cnt; ++i) {
        int e = lst[i];
        float sc = (float)scores[(size_t)e * 4 + h];
        float v  = (float)V[(size_t)e * 64 + lane];
        float mn = fmaxf(m, sc);
        float c  = __expf(m - mn);
        float ex = __expf(sc - mn);
        s = s * c + ex;
        acc = acc * c + ex * v;
        m = mn;
    }
    msg[(size_t)n * 64 + lane] = (bf16)(acc / (s + 1e-12f));
}

// ---------- N: node MLP ----------
__global__ __launch_bounds__(256, 4) void n_kernel(
    const float* __restrict__ x, const bf16* __restrict__ msg,
    const bf16* __restrict__ Wo, const bf16* __restrict__ W0, const bf16* __restrict__ W1,
    const bf16* __restrict__ W2,
    const float* __restrict__ b0, const float* __restrict__ b1, const float* __restrict__ b2,
    const float* __restrict__ ngm, const float* __restrict__ nbe,
    float* __restrict__ xout, int N)
{
    __shared__ bf16 cat[4][16][136];
    __shared__ bf16 hbl[4][16][72];
    const int w = threadIdx.x >> 6, lane = threadIdx.x & 63;
    const int nbase = blockIdx.x * 64 + w * 16;
    bf16* catw = &cat[w][0][0];
    bf16* hbw  = &hbl[w][0][0];

    {
        const int r = lane >> 2, q = lane & 3;
        const int nd = min(nbase + r, N - 1);
        const float4* xp = reinterpret_cast<const float4*>(x) + (size_t)nd * 16 + q * 4;
        stash8(catw + r * 136 + q * 16,     xp[0], xp[1]);
        stash8(catw + r * 136 + q * 16 + 8, xp[2], xp[3]);
        const bf16* mp = msg + (size_t)nd * 64 + q * 16;
        *reinterpret_cast<bf16x8*>(hbw + r * 72 + q * 16)     = *reinterpret_cast<const bf16x8*>(mp);
        *reinterpret_cast<bf16x8*>(hbw + r * 72 + q * 16 + 8) = *reinterpret_cast<const bf16x8*>(mp + 8);
    }
    const int g = lane >> 4, c16 = lane & 15;
    f32x4 acc[4];

    mm1s<72, 2>(hbw, 0, Wo, lane, acc);
#pragma unroll
    for (int n = 0; n < 4; ++n)
#pragma unroll
        for (int r = 0; r < 4; ++r)
            catw[(g * 4 + r) * 136 + 64 + n * 16 + c16] = (bf16)acc[n][r];

    mm1s<136, 4>(catw, 0, W0, lane, acc);
    storeh1(hbw, acc, b0, c16, g);
    mm1s<72, 2>(hbw, 0, W1, lane, acc);
    storeh1(hbw, acc, b1, c16, g);
    mm1s<72, 2>(hbw, 0, W2, lane, acc);
#pragma unroll
    for (int n = 0; n < 4; ++n) {
        float bb = b2[n * 16 + c16];
#pragma unroll
        for (int r = 0; r < 4; ++r) acc[n][r] += bb;
    }

    float mu[4], rs[4];
#pragma unroll
    for (int r = 0; r < 4; ++r) {
        float s1 = acc[0][r] + acc[1][r] + acc[2][r] + acc[3][r];
        for (int ms = 1; ms < 16; ms <<= 1) s1 += __shfl_xor(s1, ms);
        float mm = s1 * (1.0f / 64.0f);
        float d0 = acc[0][r] - mm, d1 = acc[1][r] - mm, d2 = acc[2][r] - mm, d3 = acc[3][r] - mm;
        float sq = d0 * d0 + d1 * d1 + d2 * d2 + d3 * d3;
        for (int ms = 1; ms < 16; ms <<= 1) sq += __shfl_xor(sq, ms);
        mu[r] = mm;
        rs[r] = rsqrtf(sq * (1.0f / 64.0f) + 1e-5f);
    }
#pragma unroll
    for (int n = 0; n < 4; ++n) {
        float gg = ngm[n * 16 + c16], bb = nbe[n * 16 + c16];
#pragma unroll
        for (int r = 0; r < 4; ++r) {
            int rowi = g * 4 + r;
            int node = nbase + rowi;
            float v = (acc[n][r] - mu[r]) * rs[r] * gg + bb;
            if (node < N) {
                size_t o = (size_t)node * 64 + n * 16 + c16;
                xout[o] = x[o] + v;
            }
        }
    }
}

// ---------- launcher ----------
extern "C" void kernel_launch(void* const* d_in, const int* in_sizes, int n_in,
                              void* d_out, int out_size, void* d_ws, size_t ws_size,
                              hipStream_t stream)
{
    const float* x   = (const float*)d_in[0];
    const int*   ei  = (const int*)d_in[1];
    const float* ea  = (const float*)d_in[2];
    const float* ew0 = (const float*)d_in[3];
    const float* eb0 = (const float*)d_in[4];
    const float* ew1 = (const float*)d_in[5];
    const float* eb1 = (const float*)d_in[6];
    const float* ew2 = (const float*)d_in[7];
    const float* eb2 = (const float*)d_in[8];
    const float* egm = (const float*)d_in[9];
    const float* ebe = (const float*)d_in[10];
    const float* nw0 = (const float*)d_in[11];
    const float* nb0 = (const float*)d_in[12];
    const float* nw1 = (const float*)d_in[13];
    const float* nb1 = (const float*)d_in[14];
    const float* nw2 = (const float*)d_in[15];
    const float* nb2 = (const float*)d_in[16];
    const float* ngm = (const float*)d_in[17];
    const float* nbe = (const float*)d_in[18];
    const float* wq  = (const float*)d_in[19];
    const float* wk  = (const float*)d_in[20];
    const float* wv  = (const float*)d_in[21];
    const float* wo  = (const float*)d_in[22];

    const int Nn = in_sizes[0] / 64;
    const int Ee = in_sizes[1] / 2;

    char* p = (char*)d_ws;
    auto carve = [&](size_t bytes) {
        char* r = p;
        p += (bytes + 255) & ~(size_t)255;
        return r;
    };
    bf16* W0e = (bf16*)carve(64 * 192 * 2);
    bf16* W1e = (bf16*)carve(64 * 64 * 2);
    bf16* W2e = (bf16*)carve(64 * 64 * 2);
    bf16* Wqb = (bf16*)carve(64 * 64 * 2);
    bf16* Wkb = (bf16*)carve(64 * 64 * 2);
    bf16* Wvb = (bf16*)carve(64 * 64 * 2);
    bf16* Wob = (bf16*)carve(64 * 64 * 2);
    bf16* W0n = (bf16*)carve(64 * 128 * 2);
    bf16* W1n = (bf16*)carve(64 * 64 * 2);
    bf16* W2n = (bf16*)carve(64 * 64 * 2);
    bf16*  scores = (bf16*)carve((size_t)Ee * 4 * 2);
    bf16*  V      = (bf16*)carve((size_t)Ee * 64 * 2);
    bf16*  msg    = (bf16*)carve((size_t)Nn * 64 * 2);
    bf16*  xb     = (bf16*)carve((size_t)Nn * 64 * 2);
    int*   deg    = (int*)carve((size_t)Nn * 4);
    int*   ofs    = (int*)carve((size_t)Nn * 4);
    int*   cur    = (int*)carve((size_t)Nn * 4);
    int*   eidT   = (int*)carve((size_t)Ee * 4);
    int*   bsum   = (int*)carve(((size_t)Nn / 256 + 2) * 4);

    hipMemsetAsync(deg, 0, (size_t)Nn * 4, stream);

    PrepArgs pa;
    const float* srcs[10] = {ew0, ew1, ew2, wq, wk, wv, wo, nw0, nw1, nw2};
    bf16* dsts[10]        = {W0e, W1e, W2e, Wqb, Wkb, Wvb, Wob, W0n, W1n, W2n};
    const int sizes[10]   = {12288, 4096, 4096, 4096, 4096, 4096, 4096, 8192, 4096, 4096};
    const int ldks[10]    = {192, 64, 64, 64, 64, 64, 64, 128, 64, 64};
    int acc_ofs = 0;
    for (int i = 0; i < 10; ++i) {
        pa.src[i] = srcs[i];
        pa.dst[i] = dsts[i];
        pa.ofs[i] = acc_ofs;
        pa.ldk[i] = ldks[i];
        acc_ofs += sizes[i];
    }
    pa.ofs[10] = acc_ofs;
    const int totalFrag = acc_ofs / 8;
    const int total8 = Nn * 64 / 8;
    const int setupTotal = totalFrag + total8 + Ee;
    setup_kernel<<<(setupTotal + 255) / 256, 256, 0, stream>>>(pa, totalFrag, x, xb, total8,
                                                               ei, deg, Ee);

    // CSR build (for gather)
    const int nb = (Nn + 255) / 256;
    scan1_kernel<<<nb, 256, 0, stream>>>(deg, ofs, bsum, Nn);
    scan2_kernel<<<1, 256, 0, stream>>>(bsum, nb);
    scan3_kernel<<<nb, 256, 0, stream>>>(ofs, bsum, cur, Nn);
    fill_kernel<<<(Ee + 255) / 256, 256, 0, stream>>>(ei, ofs, cur, eidT, Ee);

    float* xout = (float*)d_out;
    float* eout = (float*)d_out + (size_t)Nn * 64;

    // edge MLP + scores + V (original order, lane-contiguous global traffic)
    e1_kernel<<<Ee / 128, 256, 0, stream>>>(xb, ei, ea,
                                            W0e, W1e, W2e, Wqb, Wkb, Wvb,
                                            eb0, eb1, eb2, egm, ebe,
                                            scores, V, eout, Ee);

    // per-node softmax-weighted gather (random reads via eidT, L3-served)
    gather_kernel<<<(Nn + 3) / 4, 256, 0, stream>>>(deg, ofs, eidT, scores, V, msg, Nn);

    // node MLP
    n_kernel<<<(Nn + 63) / 64, 256, 0, stream>>>(x, msg, Wob, W0n, W1n, W2n,
                                                 nb0, nb1, nb2, ngm, nbe, xout, Nn);
}